// Round 1
// baseline (336.512 us; speedup 1.0000x reference)
//
#include <hip/hip_runtime.h>

// Problem constants: x(16,32,32,32,32), w(32,16,3,3,3), y(16,16,63,63,63),
// pool 4^3 over cropped 60^3 -> out(16,16,15,15,15) = 864000 fp32.
//
// Parity decomposition of stride-2 convT (pad=1, k=3):
//   even o: tap kd=1, i=o/2 ; odd o=2m+1: tap kd=0 -> i=m+1, tap kd=2 -> i=m.
//
// Block = (n, 4-od tile, 4-oh tile, full ow, all 16 cout). 256 threads:
//   k = tid&31 owns ow pair (2k, 2k+1); g = tid>>5 owns cout pair (2g, 2g+1).
//   acc[odl][ohl][owpar][c] = 64 fp32 regs per thread.

__global__ __launch_bounds__(256, 2)
void convk(const float* __restrict__ x, const float* __restrict__ w,
           const float* __restrict__ bias, float* __restrict__ pooled,
           float* __restrict__ psum, float* __restrict__ psq)
{
    const int ht = blockIdx.x, dt = blockIdx.y, n = blockIdx.z;
    const int tid = threadIdx.x;
    const int k  = tid & 31;
    const int g  = tid >> 5;        // 0..7
    const int cp = g * 2;           // cout pair base

    __shared__ float xs[2376];      // 8 ci x 3 id x 3 ih x 33 iw (pad col 32 = 0)
    __shared__ float wsh[3456];     // 8 ci x 27 tap x 16 co

    float acc[4][4][2][2] = {{{{0.f}}}};

    const int id0 = dt * 2;         // input d base
    const int ih0 = ht * 2;

    // For tap kd: which local od's use it, and which local id slot.
    static constexpr int OTAB[3][2] = {{1,3},{0,2},{1,3}};
    static constexpr int DTAB[3][2] = {{1,2},{0,1},{0,1}};

    for (int cc = 0; cc < 4; ++cc) {
        const int ci0 = cc * 8;
        __syncthreads();
        // stage x chunk
        for (int idx = tid; idx < 2376; idx += 256) {
            int ci = idx / 297;
            int r  = idx - ci * 297;
            int di = r / 99;  r -= di * 99;
            int hi = r / 33;  int iw = r - hi * 33;
            int id = id0 + di, ih = ih0 + hi;
            float v = 0.f;
            if (id < 32 && ih < 32 && iw < 32)
                v = x[(((n*32 + ci0 + ci)*32 + id)*32 + ih)*32 + iw];
            xs[idx] = v;
        }
        // stage w chunk: wsh[ci][tap][co]
        for (int idx = tid; idx < 3456; idx += 256) {
            int ci = idx / 432;
            int r  = idx - ci * 432;
            int tap = r >> 4, co = r & 15;
            wsh[idx] = w[((ci0 + ci)*16 + co)*27 + tap];
        }
        __syncthreads();

        for (int ci = 0; ci < 8; ++ci) {
            const float* xb = &xs[ci * 297];
            float xr[3][3][2];
            #pragma unroll
            for (int di = 0; di < 3; ++di)
                #pragma unroll
                for (int hi = 0; hi < 3; ++hi) {
                    xr[di][hi][0] = xb[di*99 + hi*33 + k];
                    xr[di][hi][1] = xb[di*99 + hi*33 + k + 1];
                }
            const float* wb = &wsh[ci * 432];
            #pragma unroll
            for (int kd = 0; kd < 3; ++kd) {
                #pragma unroll
                for (int kh = 0; kh < 3; ++kh) {
                    const int tb = (kd*9 + kh*3) * 16 + cp;
                    const float w0a = wb[tb +  0], w0b = wb[tb +  1];  // kw=0
                    const float w1a = wb[tb + 16], w1b = wb[tb + 17];  // kw=1
                    const float w2a = wb[tb + 32], w2b = wb[tb + 33];  // kw=2
                    #pragma unroll
                    for (int a = 0; a < 2; ++a) {
                        const int odl = OTAB[kd][a], di = DTAB[kd][a];
                        #pragma unroll
                        for (int e = 0; e < 2; ++e) {
                            const int ohl = OTAB[kh][e], hi = DTAB[kh][e];
                            const float x0 = xr[di][hi][0];   // iw = k
                            const float x1 = xr[di][hi][1];   // iw = k+1
                            // even ow = 2k: kw=1, iw=k
                            acc[odl][ohl][0][0] += x0 * w1a;
                            acc[odl][ohl][0][1] += x0 * w1b;
                            // odd ow = 2k+1: kw=0 -> iw=k+1 ; kw=2 -> iw=k
                            acc[odl][ohl][1][0] += x1 * w0a;
                            acc[odl][ohl][1][0] += x0 * w2a;
                            acc[odl][ohl][1][1] += x1 * w0b;
                            acc[odl][ohl][1][1] += x0 * w2b;
                        }
                    }
                }
            }
        }
    }

    // bias
    const float b0 = bias[cp], b1 = bias[cp + 1];
    #pragma unroll
    for (int odl = 0; odl < 4; ++odl)
        #pragma unroll
        for (int ohl = 0; ohl < 4; ++ohl) {
            acc[odl][ohl][0][0] += b0; acc[odl][ohl][1][0] += b0;
            acc[odl][ohl][0][1] += b1; acc[odl][ohl][1][1] += b1;
        }

    // ---- BN stats over valid y (od<63, oh<63; even ow always valid, odd needs k<31)
    float s0 = 0, q0 = 0, s1 = 0, q1 = 0;
    #pragma unroll
    for (int odl = 0; odl < 4; ++odl) {
        #pragma unroll
        for (int ohl = 0; ohl < 4; ++ohl) {
            const bool v2 = (4*dt + odl < 63) && (4*ht + ohl < 63);
            const float me = v2 ? 1.f : 0.f;
            const float mo = (v2 && k < 31) ? 1.f : 0.f;
            const float ve0 = acc[odl][ohl][0][0], ve1 = acc[odl][ohl][0][1];
            const float vo0 = acc[odl][ohl][1][0], vo1 = acc[odl][ohl][1][1];
            s0 += me*ve0 + mo*vo0;  q0 += me*ve0*ve0 + mo*vo0*vo0;
            s1 += me*ve1 + mo*vo1;  q1 += me*ve1*ve1 + mo*vo1*vo1;
        }
    }
    #pragma unroll
    for (int off = 16; off > 0; off >>= 1) {
        s0 += __shfl_down(s0, off, 32);
        q0 += __shfl_down(q0, off, 32);
        s1 += __shfl_down(s1, off, 32);
        q1 += __shfl_down(q1, off, 32);
    }
    const int blk = (n*16 + dt)*16 + ht;
    if (k == 0) {
        psum[ cp     *4096 + blk] = s0;
        psum[(cp + 1)*4096 + blk] = s1;
        psq [ cp     *4096 + blk] = q0;
        psq [(cp + 1)*4096 + blk] = q1;
    }

    // ---- pooling (only tiles fully inside the 60^3 crop)
    if (dt < 15 && ht < 15) {
        float p0 = 0, p1 = 0;
        #pragma unroll
        for (int odl = 0; odl < 4; ++odl)
            #pragma unroll
            for (int ohl = 0; ohl < 4; ++ohl) {
                p0 += acc[odl][ohl][0][0] + acc[odl][ohl][1][0];
                p1 += acc[odl][ohl][0][1] + acc[odl][ohl][1][1];
            }
        const float t0 = p0 + __shfl_down(p0, 1, 32);
        const float t1 = p1 + __shfl_down(p1, 1, 32);
        if ((k & 1) == 0 && k <= 28) {
            const int q  = k >> 1;
            const int sp = dt*225 + ht*15 + q;
            pooled[(n*16 + cp    )*3375 + sp] = t0 * (1.f/64.f);
            pooled[(n*16 + cp + 1)*3375 + sp] = t1 * (1.f/64.f);
        }
    }
}

__global__ void bnfinal(const float* __restrict__ psum, const float* __restrict__ psq,
                        const float* __restrict__ gamma, const float* __restrict__ beta,
                        float* __restrict__ bn)
{
    const int co = blockIdx.x;
    const int t  = threadIdx.x;
    float S = 0, Q = 0;
    for (int blk = t; blk < 4096; blk += 256) {
        S += psum[co*4096 + blk];
        Q += psq [co*4096 + blk];
    }
    #pragma unroll
    for (int off = 32; off > 0; off >>= 1) {
        S += __shfl_down(S, off, 64);
        Q += __shfl_down(Q, off, 64);
    }
    __shared__ float rs[4], rq[4];
    if ((t & 63) == 0) { rs[t >> 6] = S; rq[t >> 6] = Q; }
    __syncthreads();
    if (t == 0) {
        S = rs[0] + rs[1] + rs[2] + rs[3];
        Q = rq[0] + rq[1] + rq[2] + rq[3];
        const float cnt = 16.f * 63.f * 63.f * 63.f;
        const float mean = S / cnt;
        const float var  = Q / cnt - mean * mean;
        const float inv  = rsqrtf(var + 1e-5f);
        const float sc   = inv * gamma[co];
        bn[co]      = sc;
        bn[16 + co] = beta[co] - mean * sc;
    }
}

__global__ void finalize(const float* __restrict__ pooled, const float* __restrict__ bn,
                         float* __restrict__ out)
{
    const int i  = blockIdx.x * 256 + threadIdx.x;   // 864000 = 3375*256 exactly
    const int co = (i / 3375) & 15;
    out[i] = pooled[i] * bn[co] + bn[16 + co];
}

extern "C" void kernel_launch(void* const* d_in, const int* in_sizes, int n_in,
                              void* d_out, int out_size, void* d_ws, size_t ws_size,
                              hipStream_t stream)
{
    const float* x     = (const float*)d_in[0];
    const float* w     = (const float*)d_in[1];
    const float* b     = (const float*)d_in[2];
    const float* gamma = (const float*)d_in[3];
    const float* beta  = (const float*)d_in[4];
    float* out = (float*)d_out;

    float* wsf    = (float*)d_ws;
    float* pooled = wsf;                       // 864000
    float* psum   = wsf + 864000;              // 16*4096
    float* psq    = wsf + 864000 + 65536;      // 16*4096
    float* bn     = wsf + 864000 + 2*65536;    // 32

    dim3 grid(16, 16, 16);   // (ht, dt, n)
    convk<<<grid, 256, 0, stream>>>(x, w, b, pooled, psum, psq);
    bnfinal<<<16, 256, 0, stream>>>(psum, psq, gamma, beta, bn);
    finalize<<<3375, 256, 0, stream>>>(pooled, bn, out);
}

// Round 2
// 160.171 us; speedup vs baseline: 2.1010x; 2.1010x over previous
//
#include <hip/hip_runtime.h>

// ConvT3d(32->16, k3, s2, p1) + BN + 4^3 avgpool, fused via bf16 MFMA.
// x(16,32,32,32,32) fp32 -> xT[n][d][h][w][ci] bf16 (kernel kx)
// w(32,16,3,3,3)   fp32 -> wT[tap][co][ci]    bf16 (kernel kw)
// conv: block=(n,dt,ht): 4od x 4oh x 63ow x 16co via mfma_f32_16x16x32_bf16.
//   wave v: t=v&1 (ow 16-tile), odp=v>>1 (od pair). 54 MFMA/wave, B in regs.
// Parity decomposition (verified in round 1): even o: kw=1,i=o/2;
//   odd o=2m+1: kw=0 -> i=m+1 ; kw=2 -> i=m.

typedef __attribute__((ext_vector_type(8))) short bf16x8;
typedef __attribute__((ext_vector_type(4))) float f32x4;

static __device__ __forceinline__ unsigned short f2bf(float f) {
    unsigned int u = __float_as_uint(f);
    u = (u + 0x7fffu + ((u >> 16) & 1u)) >> 16;   // RNE
    return (unsigned short)u;
}

// ---- x transpose+convert: x[n][ci][d][h][w] fp32 -> xT[n][d][h][w][ci] bf16
__global__ __launch_bounds__(256)
void kx(const float* __restrict__ x, unsigned int* __restrict__ xTu)
{
    const int bx = blockIdx.x;            // 16*32*32
    const int n = bx >> 10, id = (bx >> 5) & 31, ih = bx & 31;
    const int tid = threadIdx.x;
    __shared__ float tile[32][33];
    #pragma unroll
    for (int it = 0; it < 4; ++it) {
        const int ci = (tid >> 5) + 8 * it, iw = tid & 31;
        tile[ci][iw] = x[((((n*32 + ci)*32 + id)*32 + ih)*32) + iw];
    }
    __syncthreads();
    const size_t obase = (size_t)(((n*32 + id)*32 + ih)*32) * 16; // uints
    #pragma unroll
    for (int it = 0; it < 2; ++it) {
        const int ci2 = tid & 15, iw = (tid >> 4) + 16 * it;
        const unsigned int lo = f2bf(tile[2*ci2    ][iw]);
        const unsigned int hi = f2bf(tile[2*ci2 + 1][iw]);
        xTu[obase + (size_t)iw * 16 + ci2] = lo | (hi << 16);
    }
}

// ---- w convert: w[ci][co][tap] fp32 -> wT[tap][co][ci] bf16 (tap=kd*9+kh*3+kw)
__global__ __launch_bounds__(256)
void kw(const float* __restrict__ w, unsigned short* __restrict__ wT)
{
    const int idx = blockIdx.x * 256 + threadIdx.x;
    if (idx < 13824) {
        const int ci = idx & 31, co = (idx >> 5) & 15, tap = idx >> 9;
        wT[idx] = f2bf(w[(ci * 16 + co) * 27 + tap]);
    }
}

// ---- fused convT + BN-stats + pool partials
__global__ __launch_bounds__(256, 2)
void convmfma(const unsigned short* __restrict__ xT,
              const unsigned short* __restrict__ wT,
              const float* __restrict__ bias,
              float* __restrict__ pooled,
              float* __restrict__ psum, float* __restrict__ psq)
{
    const int ht = blockIdx.x, dt = blockIdx.y, n = blockIdx.z;
    const int tid = threadIdx.x;
    const int v = tid >> 6, lane = tid & 63;
    const int t = v & 1, odp = v >> 1;          // ow 16-tile, od pair
    const int c = lane & 15, qd = lane >> 4;    // co, quad
    const int m = c;                            // A-row = lane&15

    // B fragments: all 27 taps in registers
    bf16x8 bfr[27];
    #pragma unroll
    for (int tp = 0; tp < 27; ++tp)
        bfr[tp] = *(const bf16x8*)(wT + tp * 512 + c * 32 + qd * 8);

    f32x4 acc[2][4][2];   // [ol][oh][par]
    #pragma unroll
    for (int ol = 0; ol < 2; ++ol)
        #pragma unroll
        for (int oh = 0; oh < 4; ++oh)
            #pragma unroll
            for (int par = 0; par < 2; ++par)
                acc[ol][oh][par] = (f32x4){0.f, 0.f, 0.f, 0.f};

    auto LOADA = [&](int di, int hi, int sofs) -> bf16x8 {
        const int id = 2*dt + di, ih = 2*ht + hi;
        const int iw = 16*t + sofs + m;
        const bf16x8 z = {};
        const bool ok = (id < 32) && (ih < 32) && (iw < 32);
        const unsigned short* p =
            xT + (size_t)(((n*32 + id)*32 + ih)*32 + iw) * 32 + qd * 8;
        return ok ? *(const bf16x8*)p : z;
    };
    auto TAP = [&](int ol, int oh, int kd, int kh, bf16x8 a0, bf16x8 a1) {
        const int tb = kd*9 + kh*3;
        acc[ol][oh][0] = __builtin_amdgcn_mfma_f32_16x16x32_bf16(
                             a0, bfr[tb + 1], acc[ol][oh][0], 0, 0, 0);
        acc[ol][oh][1] = __builtin_amdgcn_mfma_f32_16x16x32_bf16(
                             a1, bfr[tb + 0], acc[ol][oh][1], 0, 0, 0);
        acc[ol][oh][1] = __builtin_amdgcn_mfma_f32_16x16x32_bf16(
                             a0, bfr[tb + 2], acc[ol][oh][1], 0, 0, 0);
    };

    // h-tap tables: hi -> list of (kh, ohl)
    constexpr int HN[3] = {2, 3, 1};
    constexpr int HKH[3][3] = {{1,2,0},{0,1,2},{0,0,0}};
    constexpr int HOH[3][3] = {{0,1,0},{1,2,3},{3,0,0}};

    #pragma unroll
    for (int hi = 0; hi < 3; ++hi) {
        // di = odp: d-taps (kd=1 -> ol 0), (kd=2 -> ol 1)
        {
            const bf16x8 a0 = LOADA(odp, hi, 0), a1 = LOADA(odp, hi, 1);
            #pragma unroll
            for (int j = 0; j < 3; ++j)
                if (j < HN[hi]) {
                    TAP(0, HOH[hi][j], 1, HKH[hi][j], a0, a1);
                    TAP(1, HOH[hi][j], 2, HKH[hi][j], a0, a1);
                }
        }
        // di = odp+1: d-tap (kd=0 -> ol 1)
        {
            const bf16x8 a0 = LOADA(odp + 1, hi, 0), a1 = LOADA(odp + 1, hi, 1);
            #pragma unroll
            for (int j = 0; j < 3; ++j)
                if (j < HN[hi])
                    TAP(1, HOH[hi][j], 0, HKH[hi][j], a0, a1);
        }
    }

    // ---- epilogue: bias, BN stats (masked), pool partials
    const float bv = bias[c];
    float s = 0.f, sq = 0.f;
    float P[2] = {0.f, 0.f};
    #pragma unroll
    for (int ol = 0; ol < 2; ++ol) {
        const int odg = 2*odp + ol;
        const bool odok = !(dt == 15 && odg == 3);
        #pragma unroll
        for (int oh = 0; oh < 4; ++oh) {
            const bool ohok = !(ht == 15 && oh == 3);
            #pragma unroll
            for (int par = 0; par < 2; ++par) {
                #pragma unroll
                for (int r = 0; r < 4; ++r) {
                    const float val = acc[ol][oh][par][r] + bv;
                    const bool owok = !(par == 1 && t == 1 && qd == 3 && r == 3);
                    if (odok && ohok && owok) { s += val; sq += val * val; }
                    P[r >> 1] += val;
                }
            }
        }
    }
    s  += __shfl_xor(s, 16, 64);  s  += __shfl_xor(s, 32, 64);
    sq += __shfl_xor(sq, 16, 64); sq += __shfl_xor(sq, 32, 64);

    __shared__ float sred[4][16], qred[4][16], pbuf[2][8][16];
    if (lane < 16) { sred[v][lane] = s; qred[v][lane] = sq; }
    if (odp == 0 && dt < 15 && ht < 15) {
        pbuf[t][2*qd + 0][c] = P[0];
        pbuf[t][2*qd + 1][c] = P[1];
    }
    __syncthreads();
    if (tid < 16) {
        const int blk = (n*16 + dt)*16 + ht;
        psum[tid*4096 + blk] = sred[0][tid]+sred[1][tid]+sred[2][tid]+sred[3][tid];
        psq [tid*4096 + blk] = qred[0][tid]+qred[1][tid]+qred[2][tid]+qred[3][tid];
    }
    if (odp == 1 && dt < 15 && ht < 15) {
        #pragma unroll
        for (int jj = 0; jj < 2; ++jj) {
            const int jl = 2*qd + jj, jg = 8*t + jl;
            if (jg < 15) {
                const float tot = pbuf[t][jl][c] + P[jj];
                pooled[(n*16 + c)*3375 + dt*225 + ht*15 + jg] = tot * (1.f/64.f);
            }
        }
    }
}

// ================= round-1 fp32 fallback (small ws) =================
__global__ __launch_bounds__(256, 2)
void convk(const float* __restrict__ x, const float* __restrict__ w,
           const float* __restrict__ bias, float* __restrict__ pooled,
           float* __restrict__ psum, float* __restrict__ psq)
{
    const int ht = blockIdx.x, dt = blockIdx.y, n = blockIdx.z;
    const int tid = threadIdx.x;
    const int k  = tid & 31;
    const int g  = tid >> 5;
    const int cp = g * 2;
    __shared__ float xs[2376];
    __shared__ float wsh[3456];
    float acc[4][4][2][2] = {{{{0.f}}}};
    const int id0 = dt * 2, ih0 = ht * 2;
    static constexpr int OTAB[3][2] = {{1,3},{0,2},{1,3}};
    static constexpr int DTAB[3][2] = {{1,2},{0,1},{0,1}};
    for (int cc = 0; cc < 4; ++cc) {
        const int ci0 = cc * 8;
        __syncthreads();
        for (int idx = tid; idx < 2376; idx += 256) {
            int ci = idx / 297; int r = idx - ci * 297;
            int di = r / 99;  r -= di * 99;
            int hi = r / 33;  int iw = r - hi * 33;
            int id = id0 + di, ih = ih0 + hi;
            float val = 0.f;
            if (id < 32 && ih < 32 && iw < 32)
                val = x[(((n*32 + ci0 + ci)*32 + id)*32 + ih)*32 + iw];
            xs[idx] = val;
        }
        for (int idx = tid; idx < 3456; idx += 256) {
            int ci = idx / 432; int r = idx - ci * 432;
            int tap = r >> 4, co = r & 15;
            wsh[idx] = w[((ci0 + ci)*16 + co)*27 + tap];
        }
        __syncthreads();
        for (int ci = 0; ci < 8; ++ci) {
            const float* xb = &xs[ci * 297];
            float xr[3][3][2];
            #pragma unroll
            for (int di = 0; di < 3; ++di)
                #pragma unroll
                for (int hi = 0; hi < 3; ++hi) {
                    xr[di][hi][0] = xb[di*99 + hi*33 + k];
                    xr[di][hi][1] = xb[di*99 + hi*33 + k + 1];
                }
            const float* wb = &wsh[ci * 432];
            #pragma unroll
            for (int kd = 0; kd < 3; ++kd)
                #pragma unroll
                for (int kh = 0; kh < 3; ++kh) {
                    const int tb = (kd*9 + kh*3) * 16 + cp;
                    const float w0a = wb[tb +  0], w0b = wb[tb +  1];
                    const float w1a = wb[tb + 16], w1b = wb[tb + 17];
                    const float w2a = wb[tb + 32], w2b = wb[tb + 33];
                    #pragma unroll
                    for (int a = 0; a < 2; ++a) {
                        const int odl = OTAB[kd][a], di = DTAB[kd][a];
                        #pragma unroll
                        for (int e = 0; e < 2; ++e) {
                            const int ohl = OTAB[kh][e], hi = DTAB[kh][e];
                            const float x0 = xr[di][hi][0];
                            const float x1 = xr[di][hi][1];
                            acc[odl][ohl][0][0] += x0 * w1a;
                            acc[odl][ohl][0][1] += x0 * w1b;
                            acc[odl][ohl][1][0] += x1 * w0a;
                            acc[odl][ohl][1][0] += x0 * w2a;
                            acc[odl][ohl][1][1] += x1 * w0b;
                            acc[odl][ohl][1][1] += x0 * w2b;
                        }
                    }
                }
        }
    }
    const float b0 = bias[cp], b1 = bias[cp + 1];
    #pragma unroll
    for (int odl = 0; odl < 4; ++odl)
        #pragma unroll
        for (int ohl = 0; ohl < 4; ++ohl) {
            acc[odl][ohl][0][0] += b0; acc[odl][ohl][1][0] += b0;
            acc[odl][ohl][0][1] += b1; acc[odl][ohl][1][1] += b1;
        }
    float s0 = 0, q0 = 0, s1 = 0, q1 = 0;
    #pragma unroll
    for (int odl = 0; odl < 4; ++odl)
        #pragma unroll
        for (int ohl = 0; ohl < 4; ++ohl) {
            const bool v2 = (4*dt + odl < 63) && (4*ht + ohl < 63);
            const float me = v2 ? 1.f : 0.f;
            const float mo = (v2 && k < 31) ? 1.f : 0.f;
            const float ve0 = acc[odl][ohl][0][0], ve1 = acc[odl][ohl][0][1];
            const float vo0 = acc[odl][ohl][1][0], vo1 = acc[odl][ohl][1][1];
            s0 += me*ve0 + mo*vo0;  q0 += me*ve0*ve0 + mo*vo0*vo0;
            s1 += me*ve1 + mo*vo1;  q1 += me*ve1*ve1 + mo*vo1*vo1;
        }
    #pragma unroll
    for (int off = 16; off > 0; off >>= 1) {
        s0 += __shfl_down(s0, off, 32); q0 += __shfl_down(q0, off, 32);
        s1 += __shfl_down(s1, off, 32); q1 += __shfl_down(q1, off, 32);
    }
    const int blk = (n*16 + dt)*16 + ht;
    if (k == 0) {
        psum[ cp     *4096 + blk] = s0;
        psum[(cp + 1)*4096 + blk] = s1;
        psq [ cp     *4096 + blk] = q0;
        psq [(cp + 1)*4096 + blk] = q1;
    }
    if (dt < 15 && ht < 15) {
        float p0 = 0, p1 = 0;
        #pragma unroll
        for (int odl = 0; odl < 4; ++odl)
            #pragma unroll
            for (int ohl = 0; ohl < 4; ++ohl) {
                p0 += acc[odl][ohl][0][0] + acc[odl][ohl][1][0];
                p1 += acc[odl][ohl][0][1] + acc[odl][ohl][1][1];
            }
        const float t0 = p0 + __shfl_down(p0, 1, 32);
        const float t1 = p1 + __shfl_down(p1, 1, 32);
        if ((k & 1) == 0 && k <= 28) {
            const int q  = k >> 1;
            const int sp = dt*225 + ht*15 + q;
            pooled[(n*16 + cp    )*3375 + sp] = t0 * (1.f/64.f);
            pooled[(n*16 + cp + 1)*3375 + sp] = t1 * (1.f/64.f);
        }
    }
}

__global__ void bnfinal(const float* __restrict__ psum, const float* __restrict__ psq,
                        const float* __restrict__ gamma, const float* __restrict__ beta,
                        float* __restrict__ bn)
{
    const int co = blockIdx.x;
    const int t  = threadIdx.x;
    float S = 0, Q = 0;
    for (int blk = t; blk < 4096; blk += 256) {
        S += psum[co*4096 + blk];
        Q += psq [co*4096 + blk];
    }
    #pragma unroll
    for (int off = 32; off > 0; off >>= 1) {
        S += __shfl_down(S, off, 64);
        Q += __shfl_down(Q, off, 64);
    }
    __shared__ float rs[4], rq[4];
    if ((t & 63) == 0) { rs[t >> 6] = S; rq[t >> 6] = Q; }
    __syncthreads();
    if (t == 0) {
        S = rs[0] + rs[1] + rs[2] + rs[3];
        Q = rq[0] + rq[1] + rq[2] + rq[3];
        const float cnt = 16.f * 63.f * 63.f * 63.f;
        const float mean = S / cnt;
        const float var  = Q / cnt - mean * mean;
        const float inv  = rsqrtf(var + 1e-5f);
        const float sc   = inv * gamma[co];
        bn[co]      = sc;
        bn[16 + co] = beta[co] - mean * sc;
    }
}

__global__ void finalize(const float* __restrict__ pooled, const float* __restrict__ bn,
                         float* __restrict__ out)
{
    const int i  = blockIdx.x * 256 + threadIdx.x;   // 864000 = 3375*256
    const int co = (i / 3375) & 15;
    out[i] = pooled[i] * bn[co] + bn[16 + co];
}

extern "C" void kernel_launch(void* const* d_in, const int* in_sizes, int n_in,
                              void* d_out, int out_size, void* d_ws, size_t ws_size,
                              hipStream_t stream)
{
    const float* x     = (const float*)d_in[0];
    const float* w     = (const float*)d_in[1];
    const float* b     = (const float*)d_in[2];
    const float* gamma = (const float*)d_in[3];
    const float* beta  = (const float*)d_in[4];
    float* out = (float*)d_out;

    // MFMA-path ws layout (bytes)
    const size_t oXT = 0;                          // 33,554,432
    const size_t oWT = 33554432;                   // 27,648
    const size_t oPooled = oWT + 27648;            // 3,456,000
    const size_t oPsum   = oPooled + 3456000;      // 262,144
    const size_t oPsq    = oPsum + 262144;         // 262,144
    const size_t oBn     = oPsq + 262144;          // 128
    const size_t need    = oBn + 128;

    char* wsb = (char*)d_ws;
    if (ws_size >= need) {
        unsigned int*   xTu = (unsigned int*)(wsb + oXT);
        unsigned short* xT  = (unsigned short*)(wsb + oXT);
        unsigned short* wT  = (unsigned short*)(wsb + oWT);
        float* pooled = (float*)(wsb + oPooled);
        float* psum   = (float*)(wsb + oPsum);
        float* psq    = (float*)(wsb + oPsq);
        float* bn     = (float*)(wsb + oBn);

        kx<<<16384, 256, 0, stream>>>(x, xTu);
        kw<<<54, 256, 0, stream>>>(w, wT);
        dim3 grid(16, 16, 16);
        convmfma<<<grid, 256, 0, stream>>>(xT, wT, b, pooled, psum, psq);
        bnfinal<<<16, 256, 0, stream>>>(psum, psq, gamma, beta, bn);
        finalize<<<3375, 256, 0, stream>>>(pooled, bn, out);
    } else {
        float* wsf    = (float*)d_ws;
        float* pooled = wsf;
        float* psum   = wsf + 864000;
        float* psq    = wsf + 864000 + 65536;
        float* bn     = wsf + 864000 + 2*65536;
        dim3 grid(16, 16, 16);
        convk<<<grid, 256, 0, stream>>>(x, w, b, pooled, psum, psq);
        bnfinal<<<16, 256, 0, stream>>>(psum, psq, gamma, beta, bn);
        finalize<<<3375, 256, 0, stream>>>(pooled, bn, out);
    }
}

// Round 3
// 150.923 us; speedup vs baseline: 2.2297x; 1.0613x over previous
//
#include <hip/hip_runtime.h>

// ConvT3d(32->16, k3, s2, p1) + BN + 4^3 avgpool, fully fused bf16 MFMA.
// Round 3: no global transpose. Each block stages its x-halo into LDS
// (bf16, [di][hi][iw 0..32][ci], XOR-swizzled granules) and wT into LDS.
// K-loop restructured by kd-phase: only 9 B-frags (36 VGPR) live at once.
//
// Parity decomposition (validated R1/R2): even o: tap k=1, i=o/2;
//   odd o=2m+1: k=0 -> i=m+1 ; k=2 -> i=m.

typedef __attribute__((ext_vector_type(8))) short bf16x8;
typedef __attribute__((ext_vector_type(4))) float f32x4;

static __device__ __forceinline__ unsigned short f2bf(float f) {
    unsigned int u = __float_as_uint(f);
    u = (u + 0x7fffu + ((u >> 16) & 1u)) >> 16;   // RNE
    return (unsigned short)u;
}

// ---- w convert: w[ci][co][tap] fp32 -> wT[tap][co][ci] bf16 (tap=kd*9+kh*3+kw)
__global__ __launch_bounds__(256)
void kw(const float* __restrict__ w, unsigned short* __restrict__ wT)
{
    const int idx = blockIdx.x * 256 + threadIdx.x;
    if (idx < 13824) {
        const int ci = idx & 31, co = (idx >> 5) & 15, tap = idx >> 9;
        wT[idx] = f2bf(w[(ci * 16 + co) * 27 + tap]);
    }
}

// ---- fused stage + convT + BN-stats + pool partials
__global__ __launch_bounds__(256, 3)
void convf(const float* __restrict__ x,
           const unsigned short* __restrict__ wT,
           const float* __restrict__ bias,
           float* __restrict__ pooled,
           float* __restrict__ psum, float* __restrict__ psq)
{
    const int ht = blockIdx.x, dt = blockIdx.y, n = blockIdx.z;
    const int tid = threadIdx.x;
    const int v = tid >> 6, lane = tid & 63;
    const int t = v & 1, odp = v >> 1;          // ow 16-tile, od pair
    const int c = lane & 15, qd = lane >> 4;    // co (A-row m too), quad
    const int m = c;

    // xs[dihi][iw(33)][ci(32)] bf16, granule (8 ci) swizzled by (iw>>2)&3
    __shared__ unsigned short xs[9504];         // 19008 B
    __shared__ unsigned short wsm[13824];       // 27648 B
    __shared__ float sred[4][16], qred[4][16], pbuf[2][8][16];

    const int id0 = dt * 2, ih0 = ht * 2;

    // ---- zero the iw=32 halo column (reads clamp into it)
    if (tid < 144) {
        const int dihi = tid >> 4, kk = tid & 15;
        ((unsigned int*)xs)[((dihi * 1056 + 1024) >> 1) + kk] = 0u;
    }
    // ---- stage x: 288 rows (ci,dihi) x 32 floats, float4-coalesced
    for (int it = 0; it < 9; ++it) {
        const int idx = tid + 256 * it;          // < 2304
        const int row = idx >> 3, seg = idx & 7;
        const int ci = row / 9, dihi = row - ci * 9;
        const int di = dihi / 3, hi = dihi - di * 3;
        const int id = id0 + di, ih = ih0 + hi;
        float4 val = make_float4(0.f, 0.f, 0.f, 0.f);
        if (id < 32 && ih < 32)
            val = *(const float4*)(x + ((((n*32 + ci)*32 + id)*32 + ih)*32) + seg*4);
        const int g = (ci >> 3) ^ (seg & 3);
        const int base = dihi * 1056 + (seg * 4) * 32 + g * 8 + (ci & 7);
        xs[base +  0] = f2bf(val.x);
        xs[base + 32] = f2bf(val.y);
        xs[base + 64] = f2bf(val.z);
        xs[base + 96] = f2bf(val.w);
    }
    // ---- stage wT -> LDS (linear copy, uint4)
    for (int i = tid; i < 1728; i += 256)
        ((uint4*)wsm)[i] = ((const uint4*)wT)[i];
    __syncthreads();

    f32x4 acc[2][4][2];   // [ol][oh][par]
    #pragma unroll
    for (int ol = 0; ol < 2; ++ol)
        #pragma unroll
        for (int oh = 0; oh < 4; ++oh)
            #pragma unroll
            for (int par = 0; par < 2; ++par)
                acc[ol][oh][par] = (f32x4){0.f, 0.f, 0.f, 0.f};

    auto LDA = [&](int di, int hi, int sofs) -> bf16x8 {
        const int iw = 16 * t + sofs + m;
        const int g  = qd ^ ((iw >> 2) & 3);
        return *(const bf16x8*)(xs + (di*3 + hi) * 1056 + iw * 32 + g * 8);
    };
    auto LDB = [&](int tap) -> bf16x8 {
        return *(const bf16x8*)(wsm + tap * 512 + c * 32 + qd * 8);
    };

    // h-tap tables: hi -> list of (kh, ohl)
    constexpr int HN[3] = {2, 3, 1};
    constexpr int HKH[3][3] = {{1,2,0},{0,1,2},{0,0,0}};
    constexpr int HOH[3][3] = {{0,1,0},{1,2,3},{3,0,0}};

    bf16x8 A0[3], A1[3];
    #pragma unroll
    for (int hi = 0; hi < 3; ++hi) { A0[hi] = LDA(odp, hi, 0); A1[hi] = LDA(odp, hi, 1); }

    // Phase 1: di=odp -> kd=1 (ol 0), kd=2 (ol 1)
    #pragma unroll
    for (int kdi = 0; kdi < 2; ++kdi) {
        const int kd = kdi + 1, ol = kdi;
        bf16x8 Bf[3][3];
        #pragma unroll
        for (int kh = 0; kh < 3; ++kh)
            #pragma unroll
            for (int kw2 = 0; kw2 < 3; ++kw2)
                Bf[kh][kw2] = LDB(kd*9 + kh*3 + kw2);
        #pragma unroll
        for (int hi = 0; hi < 3; ++hi)
            #pragma unroll
            for (int j = 0; j < 3; ++j)
                if (j < HN[hi]) {
                    const int kh = HKH[hi][j], oh = HOH[hi][j];
                    acc[ol][oh][0] = __builtin_amdgcn_mfma_f32_16x16x32_bf16(
                        A0[hi], Bf[kh][1], acc[ol][oh][0], 0, 0, 0);
                    acc[ol][oh][1] = __builtin_amdgcn_mfma_f32_16x16x32_bf16(
                        A1[hi], Bf[kh][0], acc[ol][oh][1], 0, 0, 0);
                    acc[ol][oh][1] = __builtin_amdgcn_mfma_f32_16x16x32_bf16(
                        A0[hi], Bf[kh][2], acc[ol][oh][1], 0, 0, 0);
                }
    }

    // Phase 2: di=odp+1 -> kd=0 (ol 1)
    #pragma unroll
    for (int hi = 0; hi < 3; ++hi) { A0[hi] = LDA(odp+1, hi, 0); A1[hi] = LDA(odp+1, hi, 1); }
    {
        bf16x8 Bf[3][3];
        #pragma unroll
        for (int kh = 0; kh < 3; ++kh)
            #pragma unroll
            for (int kw2 = 0; kw2 < 3; ++kw2)
                Bf[kh][kw2] = LDB(kh*3 + kw2);
        #pragma unroll
        for (int hi = 0; hi < 3; ++hi)
            #pragma unroll
            for (int j = 0; j < 3; ++j)
                if (j < HN[hi]) {
                    const int kh = HKH[hi][j], oh = HOH[hi][j];
                    acc[1][oh][0] = __builtin_amdgcn_mfma_f32_16x16x32_bf16(
                        A0[hi], Bf[kh][1], acc[1][oh][0], 0, 0, 0);
                    acc[1][oh][1] = __builtin_amdgcn_mfma_f32_16x16x32_bf16(
                        A1[hi], Bf[kh][0], acc[1][oh][1], 0, 0, 0);
                    acc[1][oh][1] = __builtin_amdgcn_mfma_f32_16x16x32_bf16(
                        A0[hi], Bf[kh][2], acc[1][oh][1], 0, 0, 0);
                }
    }

    // ---- epilogue: bias, BN stats (masked), pool partials (validated R2)
    // C/D layout: col (co) = lane&15, spatial row = qd*4 + r.
    const float bv = bias[c];
    float s = 0.f, sq = 0.f;
    float P[2] = {0.f, 0.f};
    #pragma unroll
    for (int ol = 0; ol < 2; ++ol) {
        const int odg = 2*odp + ol;
        const bool odok = !(dt == 15 && odg == 3);
        #pragma unroll
        for (int oh = 0; oh < 4; ++oh) {
            const bool ohok = !(ht == 15 && oh == 3);
            #pragma unroll
            for (int par = 0; par < 2; ++par) {
                #pragma unroll
                for (int r = 0; r < 4; ++r) {
                    const float val = acc[ol][oh][par][r] + bv;
                    const bool owok = !(par == 1 && t == 1 && qd == 3 && r == 3);
                    if (odok && ohok && owok) { s += val; sq += val * val; }
                    P[r >> 1] += val;
                }
            }
        }
    }
    s  += __shfl_xor(s, 16, 64);  s  += __shfl_xor(s, 32, 64);
    sq += __shfl_xor(sq, 16, 64); sq += __shfl_xor(sq, 32, 64);

    if (lane < 16) { sred[v][lane] = s; qred[v][lane] = sq; }
    if (odp == 0 && dt < 15 && ht < 15) {
        pbuf[t][2*qd + 0][c] = P[0];
        pbuf[t][2*qd + 1][c] = P[1];
    }
    __syncthreads();
    if (tid < 16) {
        const int blk = (n*16 + dt)*16 + ht;
        psum[tid*4096 + blk] = sred[0][tid]+sred[1][tid]+sred[2][tid]+sred[3][tid];
        psq [tid*4096 + blk] = qred[0][tid]+qred[1][tid]+qred[2][tid]+qred[3][tid];
    }
    if (odp == 1 && dt < 15 && ht < 15) {
        #pragma unroll
        for (int jj = 0; jj < 2; ++jj) {
            const int jl = 2*qd + jj, jg = 8*t + jl;
            if (jg < 15) {
                const float tot = pbuf[t][jl][c] + P[jj];
                pooled[(n*16 + c)*3375 + dt*225 + ht*15 + jg] = tot * (1.f/64.f);
            }
        }
    }
}

__global__ void bnfinal(const float* __restrict__ psum, const float* __restrict__ psq,
                        const float* __restrict__ gamma, const float* __restrict__ beta,
                        float* __restrict__ bn)
{
    const int co = blockIdx.x;
    const int t  = threadIdx.x;
    float S = 0, Q = 0;
    for (int blk = t; blk < 4096; blk += 256) {
        S += psum[co*4096 + blk];
        Q += psq [co*4096 + blk];
    }
    #pragma unroll
    for (int off = 32; off > 0; off >>= 1) {
        S += __shfl_down(S, off, 64);
        Q += __shfl_down(Q, off, 64);
    }
    __shared__ float rs[4], rq[4];
    if ((t & 63) == 0) { rs[t >> 6] = S; rq[t >> 6] = Q; }
    __syncthreads();
    if (t == 0) {
        S = rs[0] + rs[1] + rs[2] + rs[3];
        Q = rq[0] + rq[1] + rq[2] + rq[3];
        const float cnt = 16.f * 63.f * 63.f * 63.f;
        const float mean = S / cnt;
        const float var  = Q / cnt - mean * mean;
        const float inv  = rsqrtf(var + 1e-5f);
        const float sc   = inv * gamma[co];
        bn[co]      = sc;
        bn[16 + co] = beta[co] - mean * sc;
    }
}

__global__ void finalize(const float* __restrict__ pooled, const float* __restrict__ bn,
                         float* __restrict__ out)
{
    const int i  = blockIdx.x * 256 + threadIdx.x;   // 864000 = 3375*256
    const int co = (i / 3375) & 15;
    out[i] = pooled[i] * bn[co] + bn[16 + co];
}

extern "C" void kernel_launch(void* const* d_in, const int* in_sizes, int n_in,
                              void* d_out, int out_size, void* d_ws, size_t ws_size,
                              hipStream_t stream)
{
    const float* x     = (const float*)d_in[0];
    const float* w     = (const float*)d_in[1];
    const float* b     = (const float*)d_in[2];
    const float* gamma = (const float*)d_in[3];
    const float* beta  = (const float*)d_in[4];
    float* out = (float*)d_out;

    char* wsb = (char*)d_ws;
    unsigned short* wT = (unsigned short*)wsb;        // 27,648 B
    float* pooled = (float*)(wsb + 27648);            // 3,456,000 B
    float* psum   = (float*)(wsb + 27648 + 3456000);  // 262,144 B
    float* psq    = (float*)(wsb + 27648 + 3456000 + 262144);
    float* bn     = (float*)(wsb + 27648 + 3456000 + 2*262144);

    kw<<<54, 256, 0, stream>>>(w, wT);
    dim3 grid(16, 16, 16);   // (ht, dt, n)
    convf<<<grid, 256, 0, stream>>>(x, wT, b, pooled, psum, psq);
    bnfinal<<<16, 256, 0, stream>>>(psum, psq, gamma, beta, bn);
    finalize<<<3375, 256, 0, stream>>>(pooled, bn, out);
}